// Round 6
// baseline (385.726 us; speedup 1.0000x reference)
//
#include <hip/hip_runtime.h>
#include <math.h>

#define B_  4
#define S_  2048
#define DM_ 1024
#define H_  16
#define HD_ 64

typedef float f32x4 __attribute__((ext_vector_type(4)));
typedef short bf16x8 __attribute__((ext_vector_type(8)));

#define MFMA16(a, b, c) __builtin_amdgcn_mfma_f32_16x16x32_bf16((a), (b), (c), 0, 0, 0)

static __device__ __forceinline__ unsigned short f2bf(float f) {
    union { float f; unsigned int i; } c; c.f = f;
    unsigned int u = c.i;
    return (unsigned short)((u + 0x7fffu + ((u >> 16) & 1u)) >> 16);
}
static __device__ __forceinline__ unsigned int f2u(float f) {
    union { float f; unsigned int u; } c; c.f = f; return c.u;
}

// async global->LDS, 16B per lane. lds ptr must be wave-uniform; lane i lands at l + i*16B.
static __device__ __forceinline__ void async16(const void* g, void* l) {
    __builtin_amdgcn_global_load_lds(
        (__attribute__((address_space(1))) void*)(void*)g,
        (__attribute__((address_space(3))) void*)l, 16, 0, 0);
}

// ---------------------------------------------------------------------------
// merged prep: QKV fp32->bf16 cast (blocks 0..12287), weight transpose-cast
// (12288..13311), mask prepass (13312..13343). One launch instead of three.
// ---------------------------------------------------------------------------
__global__ __launch_bounds__(256) void prep_all(
    const float* __restrict__ Q, const float* __restrict__ K,
    const float* __restrict__ V, const int* __restrict__ mask,
    const float* __restrict__ w0, const float* __restrict__ w1,
    const float* __restrict__ w2, const float* __restrict__ w3,
    unsigned short* __restrict__ qo, unsigned short* __restrict__ ko,
    unsigned short* __restrict__ vo,
    unsigned short* __restrict__ o0, unsigned short* __restrict__ o1,
    unsigned short* __restrict__ o2, unsigned short* __restrict__ o3,
    float* __restrict__ maddf, unsigned int* __restrict__ flags)
{
    __shared__ float tile[64][65];
    const int id = blockIdx.x, t = threadIdx.x;
    if (id < 12288) {                 // ---- QKV cast, 8 elems/thread ----
        const int z = id >> 12, x = id & 4095;
        const float* in = z == 0 ? Q : (z == 1 ? K : V);
        unsigned short* out = z == 0 ? qo : (z == 1 ? ko : vo);
        int idx = (x * 256 + t) * 8;
        float4 a = *(const float4*)(in + idx);
        float4 b = *(const float4*)(in + idx + 4);
        *(ushort4*)(out + idx)     = make_ushort4(f2bf(a.x), f2bf(a.y), f2bf(a.z), f2bf(a.w));
        *(ushort4*)(out + idx + 4) = make_ushort4(f2bf(b.x), f2bf(b.y), f2bf(b.z), f2bf(b.w));
    } else if (id < 13312) {          // ---- W fp32 [K][N] -> Wt bf16 [N][K] ----
        const int rr = id - 12288;
        const int z = rr >> 8, ky = (rr >> 4) & 15, nx = rr & 15;
        const float* W = z == 0 ? w0 : (z == 1 ? w1 : (z == 2 ? w2 : w3));
        unsigned short* Wt = z == 0 ? o0 : (z == 1 ? o1 : (z == 2 ? o2 : o3));
        const int k0 = ky * 64, n0 = nx * 64;
        const int r = t >> 4, c4 = (t & 15) * 4;
        #pragma unroll
        for (int s = 0; s < 4; ++s) {
            float4 f = *(const float4*)(W + (size_t)(k0 + s * 16 + r) * DM_ + n0 + c4);
            tile[s * 16 + r][c4 + 0] = f.x; tile[s * 16 + r][c4 + 1] = f.y;
            tile[s * 16 + r][c4 + 2] = f.z; tile[s * 16 + r][c4 + 3] = f.w;
        }
        __syncthreads();
        #pragma unroll
        for (int s = 0; s < 4; ++s) {
            int n = s * 16 + r;
            ushort4 o = make_ushort4(f2bf(tile[c4 + 0][n]), f2bf(tile[c4 + 1][n]),
                                     f2bf(tile[c4 + 2][n]), f2bf(tile[c4 + 3][n]));
            *(ushort4*)(Wt + (size_t)(n0 + n) * DM_ + k0 + c4) = o;
        }
    } else {                          // ---- mask prepass ----
        int i = (id - 13312) * 256 + t;
        int m = mask[i];
        maddf[i] = m ? 0.f : -__builtin_inff();
        unsigned long long bal = __ballot(m != 0);
        if ((t & 63) == 0)
            flags[i >> 6] = (bal == 0xFFFFFFFFFFFFFFFFull) ? 1u : 0u;
    }
}

// ---------------------------------------------------------------------------
// MFMA GEMM core: C[M=8192][N=1024] = A_bf16[M][K=1024] @ Wt_bf16[N][K]^T + bias
// Round-6: BM=256 x BN=128 tile, 4 waves (2x2), per-wave output 128x64
// (8 M-frags x 4 N-frags). Rationale: the per-CU LDS pipe is the binding
// resource — per c-iter this does 32 MFMA per 12 ds_read_b128 (ratio 2.67)
// vs the old 128^2 4-wave's 16/8 (2.0) and round-5 8-wave's 8/6 (1.33,
// which measured dead neutral). m201's 62%-MfmaUtil template uses exactly
// this 128x64-per-wave fragging. Single-buffered 48 KB LDS, 2-barrier
// K-loop (round-3-verified body, re-parametrized only).
// LDS rows are 64 bf16 = 128 B; 16B chunks XOR-swizzled by (row&7) so
// fragment ds_read_b128 are conflict-free (global_load_lds forbids padding).
// mode 0: bf16 out [B,H,S,64] (scaled by oscale); mode 1: bf16 out [B,H,64,S];
// mode 2: fp32 row-major
// ---------------------------------------------------------------------------
static __device__ __forceinline__ void gemm_body(
    const unsigned short* __restrict__ A,
    const unsigned short* __restrict__ Wt,
    const float* __restrict__ bias,
    void* __restrict__ outp, int mode, float oscale, int m0, int n0,
    unsigned short* As, unsigned short* Bs)
{
    const int t = threadIdx.x;
    const int w = t >> 6, l = t & 63;          // 4 waves
    const int quad = l >> 4, l16 = l & 15;
    const int wr = w >> 1, wc = w & 1;         // 2M x 2N wave grid

    // staging: wave w stages A rows [w*64, w*64+64) (8 async16) and
    // B rows [w*32, w*32+32) (4 async16), 8 rows per instr.
    // lane -> (row srow8, lds chunk l&7); source global chunk = (l&7)^srow8.
    const int srow8 = l >> 3;               // 0..7, == row&7 of the staged row
    const int sch   = (l & 7) ^ srow8;      // per-lane constant source chunk
    const unsigned short* ag = A  + (size_t)(m0 + w * 64 + srow8) * DM_ + sch * 8;
    const unsigned short* bg = Wt + (size_t)(n0 + w * 32 + srow8) * DM_ + sch * 8;

    const f32x4 fz = {0.f, 0.f, 0.f, 0.f};
    f32x4 acc[8][4];
    #pragma unroll
    for (int i = 0; i < 8; ++i)
        #pragma unroll
        for (int j = 0; j < 4; ++j) acc[i][j] = fz;

    const int rsw = l16 & 7;                // row&7 of this lane's frag rows
    for (int k0 = 0; k0 < DM_; k0 += 64) {
        __syncthreads();
        #pragma unroll
        for (int s = 0; s < 8; ++s)
            async16(ag + k0 + (size_t)(s * 8) * DM_, &As[(w * 64 + s * 8) * 64]);
        #pragma unroll
        for (int s = 0; s < 4; ++s)
            async16(bg + k0 + (size_t)(s * 8) * DM_, &Bs[(w * 32 + s * 8) * 64]);
        __syncthreads();
        #pragma unroll
        for (int c = 0; c < 2; ++c) {
            const int csw = ((c * 4 + quad) ^ rsw) * 8;
            bf16x8 af[8], bfr[4];
            #pragma unroll
            for (int i = 0; i < 8; ++i)
                af[i] = *(const bf16x8*)&As[(wr * 128 + i * 16 + l16) * 64 + csw];
            #pragma unroll
            for (int j = 0; j < 4; ++j)
                bfr[j] = *(const bf16x8*)&Bs[(wc * 64 + j * 16 + l16) * 64 + csw];
            #pragma unroll
            for (int i = 0; i < 8; ++i)
                #pragma unroll
                for (int j = 0; j < 4; ++j)
                    acc[i][j] = MFMA16(af[i], bfr[j], acc[i][j]);
        }
    }

    float bv[4];
    #pragma unroll
    for (int j = 0; j < 4; ++j) bv[j] = bias[n0 + wc * 64 + j * 16 + l16];

    if (mode == 2) {
        float* out = (float*)outp;
        #pragma unroll
        for (int i = 0; i < 8; ++i)
            #pragma unroll
            for (int j = 0; j < 4; ++j) {
                int col = n0 + wc * 64 + j * 16 + l16;
                #pragma unroll
                for (int r = 0; r < 4; ++r) {
                    int row = m0 + wr * 128 + i * 16 + quad * 4 + r;
                    out[(size_t)row * DM_ + col] = acc[i][j][r] + bv[j];
                }
            }
    } else if (mode == 0) {   // [B,H,S,64] bf16, scaled
        unsigned short* out = (unsigned short*)outp;
        #pragma unroll
        for (int i = 0; i < 8; ++i)
            #pragma unroll
            for (int j = 0; j < 4; ++j) {
                int col = n0 + wc * 64 + j * 16 + l16;
                int h = col >> 6, d = col & 63;
                #pragma unroll
                for (int r = 0; r < 4; ++r) {
                    int row = m0 + wr * 128 + i * 16 + quad * 4 + r;
                    int bb = row >> 11, ss = row & (S_ - 1);
                    out[(((size_t)bb * H_ + h) * S_ + ss) * HD_ + d] =
                        f2bf((acc[i][j][r] + bv[j]) * oscale);
                }
            }
    } else {                  // mode 1: [B,H,64,S] bf16, pack 4 consecutive s
        unsigned short* out = (unsigned short*)outp;
        #pragma unroll
        for (int i = 0; i < 8; ++i)
            #pragma unroll
            for (int j = 0; j < 4; ++j) {
                int col = n0 + wc * 64 + j * 16 + l16;
                int h = col >> 6, d = col & 63;
                int row0 = m0 + wr * 128 + i * 16 + quad * 4;
                int bb = row0 >> 11, ss = row0 & (S_ - 1);
                ushort4 o = make_ushort4(f2bf(acc[i][j][0] + bv[j]),
                                         f2bf(acc[i][j][1] + bv[j]),
                                         f2bf(acc[i][j][2] + bv[j]),
                                         f2bf(acc[i][j][3] + bv[j]));
                *(ushort4*)(out + (((size_t)bb * H_ + h) * HD_ + d) * S_ + ss) = o;
            }
    }
}

// fused Q/K/V projection, 1D grid of 768 with XCD swizzle: block id d goes to
// XCD d%8; role = (d&7)*96 + d>>3 gives each XCD a contiguous run of roles, so
// the 8 N-blocks sharing one 512KB A-tile land on ONE XCD's L2. Bijective:
// 768 = 8*96. role: z = role>>8, m-block = (role&255)>>3, n-block = role&7.
// q output is pre-scaled by 0.125*log2(e) so attn softmax is exp2(sc) directly.
__global__ __launch_bounds__(256) void gemm_qkv3(
    const unsigned short* __restrict__ Qc, const unsigned short* __restrict__ Kc,
    const unsigned short* __restrict__ Vc,
    const unsigned short* __restrict__ Wqt, const unsigned short* __restrict__ Wkt,
    const unsigned short* __restrict__ Wvt,
    const float* __restrict__ bq, const float* __restrict__ bk,
    const float* __restrict__ bvp,
    unsigned short* __restrict__ qh, unsigned short* __restrict__ kh,
    unsigned short* __restrict__ vth)
{
    __shared__ unsigned short As[256 * 64];   // 32 KB
    __shared__ unsigned short Bs[128 * 64];   // 16 KB
    const int id = blockIdx.x;
    const int role = (id & 7) * 96 + (id >> 3);
    const int z = role >> 8, r2 = role & 255;
    const int m0 = (r2 >> 3) * 256, n0 = (r2 & 7) * 128;
    const unsigned short* A  = z == 0 ? Qc  : (z == 1 ? Kc  : Vc);
    const unsigned short* Wt = z == 0 ? Wqt : (z == 1 ? Wkt : Wvt);
    const float* bias        = z == 0 ? bq  : (z == 1 ? bk  : bvp);
    void* out                = z == 0 ? (void*)qh : (z == 1 ? (void*)kh : (void*)vth);
    const float qsc = 0.18033688011112042f;   // 0.125 * log2(e)
    gemm_body(A, Wt, bias, out, z == 2 ? 1 : 0, z == 0 ? qsc : 1.0f, m0, n0, As, Bs);
}

__global__ __launch_bounds__(256) void gemm_omfma(
    const unsigned short* __restrict__ A, const unsigned short* __restrict__ Wt,
    const float* __restrict__ bias, float* __restrict__ out)
{
    __shared__ unsigned short As[256 * 64];
    __shared__ unsigned short Bs[128 * 64];
    const int id = blockIdx.x;                // 256 = 8*32, bijective swizzle
    const int role = (id & 7) * 32 + (id >> 3);
    const int m0 = (role >> 3) * 256, n0 = (role & 7) * 128;
    gemm_body(A, Wt, bias, out, 2, 1.0f, m0, n0, As, Bs);
}

// ---------------------------------------------------------------------------
// softmax + P-store helper (MASKED adds precomputed {0,-inf}); Q pre-scaled,
// so fast path is a bare exp2. Truncate-pack to bf16. No l accumulation here:
// the row-sum comes from an extra ones-B MFMA in the PV phase (matrix pipe
// has headroom; VALU is the busy pipe).
// ---------------------------------------------------------------------------
template<bool MASKED>
static __device__ __forceinline__ void softmax_store(
    const f32x4* sc, const float (*madd)[4], unsigned short* Pg,
    int l16, int quad, int rsw)
{
    #pragma unroll
    for (int kk = 0; kk < 4; ++kk) {
        int kb = (kk * 2 + (quad >> 1)) ^ rsw;
        #pragma unroll
        for (int rp = 0; rp < 2; ++rp) {
            float a0 = sc[kk][rp * 2 + 0], a1 = sc[kk][rp * 2 + 1];
            if (MASKED) { a0 += madd[kk][rp * 2 + 0]; a1 += madd[kk][rp * 2 + 1]; }
            float p0 = __builtin_amdgcn_exp2f(a0);
            float p1 = __builtin_amdgcn_exp2f(a1);
            unsigned int pk = __builtin_amdgcn_perm(f2u(p1), f2u(p0), 0x07060302u);
            *(unsigned int*)&Pg[l16 * 64 + kb * 8 + (quad & 1) * 4 + rp * 2] = pk;
        }
    }
}

// ---------------------------------------------------------------------------
// MFMA flash attention, transposed scores (K.Q^T so each lane owns one q-row's
// scores). Unchanged from round 3 (107.6 us, ~640 TF effective).
// ---------------------------------------------------------------------------
__global__ __launch_bounds__(256) void attn_mfma(
    const unsigned short* __restrict__ q,
    const unsigned short* __restrict__ k,
    const unsigned short* __restrict__ vt,
    const float* __restrict__ maddf,
    const unsigned int* __restrict__ flags,
    unsigned short* __restrict__ out)
{
    __shared__ unsigned short Ks[2][64 * 64];    // 16 KB
    __shared__ unsigned short Vs[2][64 * 64];    // 16 KB [dv][key]
    __shared__ unsigned short Ps[4][2][16 * 64]; // 16 KB, per wave per q-group
    const int t = threadIdx.x;
    const int w = t >> 6, l = t & 63;
    const int quad = l >> 4, l16 = l & 15;

    const int bid = blockIdx.x;                  // 1024 blocks
    const int swz = (bid & 7) * 128 + (bid >> 3);
    const int qb = swz & 15, h = (swz >> 4) & 15, b = swz >> 8;
    const int q0 = qb * 128;
    const size_t hb = ((size_t)b * H_ + h) * S_;

    const int srow8 = l >> 3;
    const int sch   = (l & 7) ^ srow8;
    const int rsw   = l16 & 7;

    // Q fragments direct from global (pre-scaled by 0.125*log2e in projection)
    const unsigned short* qg = q + (hb + q0) * HD_;
    bf16x8 qf[2][2];   // [q-group][d-half], B-operand frags (row-major [q][d])
    #pragma unroll
    for (int g = 0; g < 2; ++g)
        #pragma unroll
        for (int c = 0; c < 2; ++c)
            qf[g][c] = *(const bf16x8*)(qg +
                (size_t)(w * 32 + g * 16 + l16) * HD_ + (c * 4 + quad) * 8);

    const bf16x8 onesf = {(short)0x3F80, (short)0x3F80, (short)0x3F80, (short)0x3F80,
                          (short)0x3F80, (short)0x3F80, (short)0x3F80, (short)0x3F80};

    const f32x4 fz = {0.f, 0.f, 0.f, 0.f};
    f32x4 o[2][4];
    f32x4 ol[2] = {fz, fz};                      // ones-MFMA row-sum accumulator
    #pragma unroll
    for (int g = 0; g < 2; ++g)
        #pragma unroll
        for (int jv = 0; jv < 4; ++jv) o[g][jv] = fz;

    const unsigned short* kg0 = k + hb * HD_;
    const unsigned short* vg0 = vt + ((size_t)b * H_ + h) * HD_ * S_;

    // stage K/V tile kt into buffer d (swizzled 16B chunks, 2 async16 each)
    auto stage = [&](int d, int kt) {
        #pragma unroll
        for (int s = 0; s < 2; ++s) {
            int r0 = w * 16 + s * 8;
            int rr = r0 + srow8;
            async16(kg0 + (size_t)(kt * 64 + rr) * HD_ + sch * 8, &Ks[d][r0 * 64]);
            async16(vg0 + (size_t)rr * S_ + kt * 64 + sch * 8, &Vs[d][r0 * 64]);
        }
    };

    stage(0, 0);
    int cur = 0;
    for (int kt = 0; kt < S_ / 64; ++kt) {
        // drains the in-flight global_load_lds for buf[cur] (compiler emits
        // vmcnt(0) before s_barrier) and joins all waves past last tile's use
        // of buf[cur^1].
        __syncthreads();
        if (kt + 1 < S_ / 64) stage(cur ^ 1, kt + 1);

        const int allv = flags[b * (S_ / 64) + kt];   // uniform -> scalar load
        float madd[4][4];
        if (!allv) {
            #pragma unroll
            for (int kk = 0; kk < 4; ++kk) {
                float4 mv = *(const float4*)&maddf[(size_t)b * S_ + kt * 64 + kk * 16 + quad * 4];
                madd[kk][0] = mv.x; madd[kk][1] = mv.y;
                madd[kk][2] = mv.z; madd[kk][3] = mv.w;
            }
        }

        // ---- phase 1: K frags, QK^T + softmax for both groups ----
        const unsigned short* Kc = &Ks[cur][0];
        bf16x8 kf[4][2];
        #pragma unroll
        for (int kk = 0; kk < 4; ++kk) {
            int row = kk * 16 + l16;
            #pragma unroll
            for (int c = 0; c < 2; ++c)
                kf[kk][c] = *(const bf16x8*)&Kc[row * 64 + (((c * 4 + quad) ^ rsw) * 8)];
        }
        #pragma unroll
        for (int g = 0; g < 2; ++g) {
            // scores: D[key = kk*16 + quad*4 + r][q = g*16 + l16]
            f32x4 sc[4];
            #pragma unroll
            for (int kk = 0; kk < 4; ++kk) sc[kk] = fz;
            __builtin_amdgcn_s_setprio(1);
            #pragma unroll
            for (int kk = 0; kk < 4; ++kk) {
                sc[kk] = MFMA16(kf[kk][0], qf[g][0], sc[kk]);
                sc[kk] = MFMA16(kf[kk][1], qf[g][1], sc[kk]);
            }
            __builtin_amdgcn_s_setprio(0);
            if (allv) softmax_store<false>(sc, madd, &Ps[w][g][0], l16, quad, rsw);
            else      softmax_store<true >(sc, madd, &Ps[w][g][0], l16, quad, rsw);
        }

        // ---- phase 2: V frags, PV (+ ones row-sum) for both groups ----
        const unsigned short* Vc = &Vs[cur][0];
        bf16x8 vfr[4][2];
        #pragma unroll
        for (int jv = 0; jv < 4; ++jv) {
            int row = jv * 16 + l16;
            #pragma unroll
            for (int c = 0; c < 2; ++c)
                vfr[jv][c] = *(const bf16x8*)&Vc[row * 64 + (((c * 4 + quad) ^ rsw) * 8)];
        }
        #pragma unroll
        for (int g = 0; g < 2; ++g) {
            // PV: A = P^[q=l16][key], B = V rows [dv][key]; O D[q=quad*4+r][dv=l16]
            bf16x8 pa0 = *(const bf16x8*)&Ps[w][g][l16 * 64 + ((quad ^ rsw) * 8)];
            bf16x8 pa1 = *(const bf16x8*)&Ps[w][g][l16 * 64 + (((4 + quad) ^ rsw) * 8)];
            __builtin_amdgcn_s_setprio(1);
            #pragma unroll
            for (int jv = 0; jv < 4; ++jv) {
                o[g][jv] = MFMA16(pa0, vfr[jv][0], o[g][jv]);
                o[g][jv] = MFMA16(pa1, vfr[jv][1], o[g][jv]);
            }
            ol[g] = MFMA16(pa0, onesf, ol[g]);
            ol[g] = MFMA16(pa1, onesf, ol[g]);
            __builtin_amdgcn_s_setprio(0);
        }
        cur ^= 1;
    }

    // epilogue: ol[g][r] = full row sum for q-row (g, quad*4+r); no shuffles.
    #pragma unroll
    for (int g = 0; g < 2; ++g) {
        float inv[4];
        #pragma unroll
        for (int r = 0; r < 4; ++r) inv[r] = 1.0f / ol[g][r];
        #pragma unroll
        for (int jv = 0; jv < 4; ++jv) {
            int col = h * HD_ + jv * 16 + l16;
            #pragma unroll
            for (int r = 0; r < 4; ++r) {
                int row = q0 + w * 32 + g * 16 + quad * 4 + r;
                out[((size_t)b * S_ + row) * DM_ + col] = f2bf(o[g][jv][r] * inv[r]);
            }
        }
    }
}

extern "C" void kernel_launch(void* const* d_in, const int* in_sizes, int n_in,
                              void* d_out, int out_size, void* d_ws, size_t ws_size,
                              hipStream_t stream) {
    const float* Q    = (const float*)d_in[0];
    const float* K    = (const float*)d_in[1];
    const float* V    = (const float*)d_in[2];
    const int*   mask = (const int*)d_in[3];
    const float* Wq   = (const float*)d_in[4];
    const float* bq   = (const float*)d_in[5];
    const float* Wk   = (const float*)d_in[6];
    const float* bk   = (const float*)d_in[7];
    const float* Wv   = (const float*)d_in[8];
    const float* bv   = (const float*)d_in[9];
    const float* Wo   = (const float*)d_in[10];
    const float* bo   = (const float*)d_in[11];

    char* ws = (char*)d_ws;
    const size_t MB = 1024 * 1024;
    unsigned short* Qc  = (unsigned short*)(ws);            // 16 MB each
    unsigned short* Kc  = (unsigned short*)(ws + 16 * MB);
    unsigned short* Vc  = (unsigned short*)(ws + 32 * MB);
    unsigned short* Wqt = (unsigned short*)(ws + 48 * MB);  // 2 MB each
    unsigned short* Wkt = (unsigned short*)(ws + 50 * MB);
    unsigned short* Wvt = (unsigned short*)(ws + 52 * MB);
    unsigned short* Wot = (unsigned short*)(ws + 54 * MB);
    unsigned short* qh  = (unsigned short*)(ws + 56 * MB);  // [B,H,S,64]
    unsigned short* kh  = (unsigned short*)(ws + 72 * MB);
    unsigned short* vth = (unsigned short*)(ws + 88 * MB);  // [B,H,64,S]
    unsigned short* ao  = (unsigned short*)(ws + 104 * MB); // [B,S,DM]
    float*          maddf = (float*)(ws + 120 * MB);        // 32 KB
    unsigned int*   flagsb = (unsigned int*)(ws + 120 * MB + 64 * 1024); // 512 B

    prep_all<<<dim3(13344), 256, 0, stream>>>(
        Q, K, V, mask, Wq, Wk, Wv, Wo,
        Qc, Kc, Vc, Wqt, Wkt, Wvt, Wot, maddf, flagsb);
    gemm_qkv3<<<dim3(768), 256, 0, stream>>>(
        Qc, Kc, Vc, Wqt, Wkt, Wvt, bq, bk, bv, qh, kh, vth);
    attn_mfma<<<dim3(1024), 256, 0, stream>>>(
        qh, kh, vth, maddf, flagsb, ao);
    gemm_omfma<<<dim3(256), 256, 0, stream>>>(ao, Wot, bo, (float*)d_out);
}

// Round 7
// 333.922 us; speedup vs baseline: 1.1551x; 1.1551x over previous
//
#include <hip/hip_runtime.h>
#include <math.h>

#define B_  4
#define S_  2048
#define DM_ 1024
#define H_  16
#define HD_ 64

typedef float f32x4 __attribute__((ext_vector_type(4)));
typedef short bf16x8 __attribute__((ext_vector_type(8)));

#define MFMA16(a, b, c) __builtin_amdgcn_mfma_f32_16x16x32_bf16((a), (b), (c), 0, 0, 0)

static __device__ __forceinline__ unsigned short f2bf(float f) {
    union { float f; unsigned int i; } c; c.f = f;
    unsigned int u = c.i;
    return (unsigned short)((u + 0x7fffu + ((u >> 16) & 1u)) >> 16);
}
static __device__ __forceinline__ unsigned int f2u(float f) {
    union { float f; unsigned int u; } c; c.f = f; return c.u;
}

// async global->LDS, 16B per lane. lds ptr must be wave-uniform; lane i lands at l + i*16B.
static __device__ __forceinline__ void async16(const void* g, void* l) {
    __builtin_amdgcn_global_load_lds(
        (__attribute__((address_space(1))) void*)(void*)g,
        (__attribute__((address_space(3))) void*)l, 16, 0, 0);
}

// ---------------------------------------------------------------------------
// merged prep: QKV fp32->bf16 cast (blocks 0..12287), weight transpose-cast
// (12288..13311), mask prepass (13312..13343). One launch instead of three.
// ---------------------------------------------------------------------------
__global__ __launch_bounds__(256) void prep_all(
    const float* __restrict__ Q, const float* __restrict__ K,
    const float* __restrict__ V, const int* __restrict__ mask,
    const float* __restrict__ w0, const float* __restrict__ w1,
    const float* __restrict__ w2, const float* __restrict__ w3,
    unsigned short* __restrict__ qo, unsigned short* __restrict__ ko,
    unsigned short* __restrict__ vo,
    unsigned short* __restrict__ o0, unsigned short* __restrict__ o1,
    unsigned short* __restrict__ o2, unsigned short* __restrict__ o3,
    float* __restrict__ maddf, unsigned int* __restrict__ flags)
{
    __shared__ float tile[64][65];
    const int id = blockIdx.x, t = threadIdx.x;
    if (id < 12288) {                 // ---- QKV cast, 8 elems/thread ----
        const int z = id >> 12, x = id & 4095;
        const float* in = z == 0 ? Q : (z == 1 ? K : V);
        unsigned short* out = z == 0 ? qo : (z == 1 ? ko : vo);
        int idx = (x * 256 + t) * 8;
        float4 a = *(const float4*)(in + idx);
        float4 b = *(const float4*)(in + idx + 4);
        *(ushort4*)(out + idx)     = make_ushort4(f2bf(a.x), f2bf(a.y), f2bf(a.z), f2bf(a.w));
        *(ushort4*)(out + idx + 4) = make_ushort4(f2bf(b.x), f2bf(b.y), f2bf(b.z), f2bf(b.w));
    } else if (id < 13312) {          // ---- W fp32 [K][N] -> Wt bf16 [N][K] ----
        const int rr = id - 12288;
        const int z = rr >> 8, ky = (rr >> 4) & 15, nx = rr & 15;
        const float* W = z == 0 ? w0 : (z == 1 ? w1 : (z == 2 ? w2 : w3));
        unsigned short* Wt = z == 0 ? o0 : (z == 1 ? o1 : (z == 2 ? o2 : o3));
        const int k0 = ky * 64, n0 = nx * 64;
        const int r = t >> 4, c4 = (t & 15) * 4;
        #pragma unroll
        for (int s = 0; s < 4; ++s) {
            float4 f = *(const float4*)(W + (size_t)(k0 + s * 16 + r) * DM_ + n0 + c4);
            tile[s * 16 + r][c4 + 0] = f.x; tile[s * 16 + r][c4 + 1] = f.y;
            tile[s * 16 + r][c4 + 2] = f.z; tile[s * 16 + r][c4 + 3] = f.w;
        }
        __syncthreads();
        #pragma unroll
        for (int s = 0; s < 4; ++s) {
            int n = s * 16 + r;
            ushort4 o = make_ushort4(f2bf(tile[c4 + 0][n]), f2bf(tile[c4 + 1][n]),
                                     f2bf(tile[c4 + 2][n]), f2bf(tile[c4 + 3][n]));
            *(ushort4*)(Wt + (size_t)(n0 + n) * DM_ + k0 + c4) = o;
        }
    } else {                          // ---- mask prepass ----
        int i = (id - 13312) * 256 + t;
        int m = mask[i];
        maddf[i] = m ? 0.f : -__builtin_inff();
        unsigned long long bal = __ballot(m != 0);
        if ((t & 63) == 0)
            flags[i >> 6] = (bal == 0xFFFFFFFFFFFFFFFFull) ? 1u : 0u;
    }
}

// ---------------------------------------------------------------------------
// MFMA GEMM core — REVERTED to the round-5 equal-best config (round 6's
// 256x128 single-buffer re-parametrization cost +44 us; register-capped).
// 128x128 tile, BK=64, 8 waves / 512 threads (wave grid 2M x 4N, per-wave
// output 64x32, acc 4x2), double-buffered LDS (one barrier per K-step; next
// tile's global_load_lds issued right after the barrier, drained by the NEXT
// iteration's barrier). __launch_bounds__(512,4) caps regs at 128.
// LDS rows are 64 bf16 = 128 B; 16B chunks XOR-swizzled by (row&7) so
// fragment ds_read_b128 are conflict-free (global_load_lds forbids padding).
// mode 0: bf16 out [B,H,S,64] (scaled by oscale); mode 1: bf16 out [B,H,64,S];
// mode 2: fp32 row-major
// ---------------------------------------------------------------------------
static __device__ __forceinline__ void gemm_body(
    const unsigned short* __restrict__ A,
    const unsigned short* __restrict__ Wt,
    const float* __restrict__ bias,
    void* __restrict__ outp, int mode, float oscale, int m0, int n0,
    unsigned short (*As)[128 * 64], unsigned short (*Bs)[128 * 64])
{
    const int t = threadIdx.x;
    const int w = t >> 6, l = t & 63;          // 8 waves
    const int quad = l >> 4, l16 = l & 15;
    const int wr = w >> 2, wc = w & 3;         // 2M x 4N wave grid

    // staging: wave w stages rows [w*16, w*16+16) of both tiles, 8 rows/instr.
    // lane -> (row srow8, lds chunk l&7); source global chunk = (l&7)^srow8.
    const int srow8 = l >> 3;               // 0..7, == row&7 of the staged row
    const int sch   = (l & 7) ^ srow8;      // per-lane constant source chunk
    const unsigned short* ag = A  + (size_t)(m0 + w * 16 + srow8) * DM_ + sch * 8;
    const unsigned short* bg = Wt + (size_t)(n0 + w * 16 + srow8) * DM_ + sch * 8;

    const f32x4 fz = {0.f, 0.f, 0.f, 0.f};
    f32x4 acc[4][2];
    #pragma unroll
    for (int i = 0; i < 4; ++i)
        #pragma unroll
        for (int j = 0; j < 2; ++j) acc[i][j] = fz;

    const int rsw = l16 & 7;                // row&7 of this lane's frag rows

    auto stageAB = [&](int d, int k0) {
        #pragma unroll
        for (int s = 0; s < 2; ++s) {
            async16(ag + k0 + (size_t)(s * 8) * DM_, &As[d][(w * 16 + s * 8) * 64]);
            async16(bg + k0 + (size_t)(s * 8) * DM_, &Bs[d][(w * 16 + s * 8) * 64]);
        }
    };

    stageAB(0, 0);
    int cur = 0;
    for (int k0 = 0; k0 < DM_; k0 += 64) {
        // barrier's vmcnt(0) drains the in-flight loads for buf[cur]; also
        // joins all waves past last iteration's reads of buf[cur^1].
        __syncthreads();
        if (k0 + 64 < DM_) stageAB(cur ^ 1, k0 + 64);
        #pragma unroll
        for (int c = 0; c < 2; ++c) {
            const int csw = ((c * 4 + quad) ^ rsw) * 8;
            bf16x8 af[4], bfr[2];
            #pragma unroll
            for (int i = 0; i < 4; ++i)
                af[i] = *(const bf16x8*)&As[cur][(wr * 64 + i * 16 + l16) * 64 + csw];
            #pragma unroll
            for (int j = 0; j < 2; ++j)
                bfr[j] = *(const bf16x8*)&Bs[cur][(wc * 32 + j * 16 + l16) * 64 + csw];
            #pragma unroll
            for (int i = 0; i < 4; ++i)
                #pragma unroll
                for (int j = 0; j < 2; ++j)
                    acc[i][j] = MFMA16(af[i], bfr[j], acc[i][j]);
        }
        cur ^= 1;
    }

    float bv[2];
    #pragma unroll
    for (int j = 0; j < 2; ++j) bv[j] = bias[n0 + wc * 32 + j * 16 + l16];

    if (mode == 2) {
        float* out = (float*)outp;
        #pragma unroll
        for (int i = 0; i < 4; ++i)
            #pragma unroll
            for (int j = 0; j < 2; ++j) {
                int col = n0 + wc * 32 + j * 16 + l16;
                #pragma unroll
                for (int r = 0; r < 4; ++r) {
                    int row = m0 + wr * 64 + i * 16 + quad * 4 + r;
                    out[(size_t)row * DM_ + col] = acc[i][j][r] + bv[j];
                }
            }
    } else if (mode == 0) {   // [B,H,S,64] bf16, scaled
        unsigned short* out = (unsigned short*)outp;
        #pragma unroll
        for (int i = 0; i < 4; ++i)
            #pragma unroll
            for (int j = 0; j < 2; ++j) {
                int col = n0 + wc * 32 + j * 16 + l16;
                int h = col >> 6, d = col & 63;
                #pragma unroll
                for (int r = 0; r < 4; ++r) {
                    int row = m0 + wr * 64 + i * 16 + quad * 4 + r;
                    int bb = row >> 11, ss = row & (S_ - 1);
                    out[(((size_t)bb * H_ + h) * S_ + ss) * HD_ + d] =
                        f2bf((acc[i][j][r] + bv[j]) * oscale);
                }
            }
    } else {                  // mode 1: [B,H,64,S] bf16, pack 4 consecutive s
        unsigned short* out = (unsigned short*)outp;
        #pragma unroll
        for (int i = 0; i < 4; ++i)
            #pragma unroll
            for (int j = 0; j < 2; ++j) {
                int col = n0 + wc * 32 + j * 16 + l16;
                int h = col >> 6, d = col & 63;
                int row0 = m0 + wr * 64 + i * 16 + quad * 4;
                int bb = row0 >> 11, ss = row0 & (S_ - 1);
                ushort4 o = make_ushort4(f2bf(acc[i][j][0] + bv[j]),
                                         f2bf(acc[i][j][1] + bv[j]),
                                         f2bf(acc[i][j][2] + bv[j]),
                                         f2bf(acc[i][j][3] + bv[j]));
                *(ushort4*)(out + (((size_t)bb * H_ + h) * HD_ + d) * S_ + ss) = o;
            }
    }
}

// fused Q/K/V projection, 1D grid of 1536 with XCD swizzle (bijective, 1536 =
// 8*192): the 8 N-blocks sharing one 256KB A-tile land on ONE XCD's L2.
// q output is pre-scaled by 0.125*log2(e) so attn softmax is exp2(sc) directly.
__global__ __launch_bounds__(512, 4) void gemm_qkv3(
    const unsigned short* __restrict__ Qc, const unsigned short* __restrict__ Kc,
    const unsigned short* __restrict__ Vc,
    const unsigned short* __restrict__ Wqt, const unsigned short* __restrict__ Wkt,
    const unsigned short* __restrict__ Wvt,
    const float* __restrict__ bq, const float* __restrict__ bk,
    const float* __restrict__ bvp,
    unsigned short* __restrict__ qh, unsigned short* __restrict__ kh,
    unsigned short* __restrict__ vth)
{
    __shared__ unsigned short As[2][128 * 64];
    __shared__ unsigned short Bs[2][128 * 64];
    const int id = blockIdx.x;
    const int role = (id & 7) * 192 + (id >> 3);
    const int z = role >> 9, r2 = role & 511;
    const int m0 = (r2 >> 3) * 128, n0 = (r2 & 7) * 128;
    const unsigned short* A  = z == 0 ? Qc  : (z == 1 ? Kc  : Vc);
    const unsigned short* Wt = z == 0 ? Wqt : (z == 1 ? Wkt : Wvt);
    const float* bias        = z == 0 ? bq  : (z == 1 ? bk  : bvp);
    void* out                = z == 0 ? (void*)qh : (z == 1 ? (void*)kh : (void*)vth);
    const float qsc = 0.18033688011112042f;   // 0.125 * log2(e)
    gemm_body(A, Wt, bias, out, z == 2 ? 1 : 0, z == 0 ? qsc : 1.0f, m0, n0, As, Bs);
}

__global__ __launch_bounds__(512, 4) void gemm_omfma(
    const unsigned short* __restrict__ A, const unsigned short* __restrict__ Wt,
    const float* __restrict__ bias, float* __restrict__ out)
{
    __shared__ unsigned short As[2][128 * 64];
    __shared__ unsigned short Bs[2][128 * 64];
    const int id = blockIdx.x;                // 512 = 8*64, bijective swizzle
    const int role = (id & 7) * 64 + (id >> 3);
    const int m0 = (role >> 3) * 128, n0 = (role & 7) * 128;
    gemm_body(A, Wt, bias, out, 2, 1.0f, m0, n0, As, Bs);
}

// ---------------------------------------------------------------------------
// softmax + P-store helper (MASKED adds precomputed {0,-inf}); Q pre-scaled,
// so fast path is a bare exp2. Truncate-pack to bf16. Round-7: the two
// adjacent pk words are packed into ONE ds_write_b64 (halves P-store ops on
// the LDS pipe). No l accumulation here: row-sum via ones-B MFMA in PV.
// ---------------------------------------------------------------------------
template<bool MASKED>
static __device__ __forceinline__ void softmax_store(
    const f32x4* sc, const float (*madd)[4], unsigned short* Pg,
    int l16, int quad, int rsw)
{
    #pragma unroll
    for (int kk = 0; kk < 4; ++kk) {
        int kb = (kk * 2 + (quad >> 1)) ^ rsw;
        unsigned int pk[2];
        #pragma unroll
        for (int rp = 0; rp < 2; ++rp) {
            float a0 = sc[kk][rp * 2 + 0], a1 = sc[kk][rp * 2 + 1];
            if (MASKED) { a0 += madd[kk][rp * 2 + 0]; a1 += madd[kk][rp * 2 + 1]; }
            float p0 = __builtin_amdgcn_exp2f(a0);
            float p1 = __builtin_amdgcn_exp2f(a1);
            pk[rp] = __builtin_amdgcn_perm(f2u(p1), f2u(p0), 0x07060302u);
        }
        *(unsigned long long*)&Pg[l16 * 64 + kb * 8 + (quad & 1) * 4] =
            (unsigned long long)pk[0] | ((unsigned long long)pk[1] << 32);
    }
}

// ---------------------------------------------------------------------------
// MFMA flash attention. Round-7: QBLK 128 -> 256 (4 waves x 4 q-groups).
// Rationale (round-6 PMC arithmetic): the kernel is LDS-pipe-bound — per
// block-iter the 4 waves issue identical K/V fragment reads (redundant) plus
// P round-trips ≈ 1700 cyc/CU-iter vs ~180 cyc MFMA. Doubling Q rows per
// block amortizes K/V frag reads, staging DMA, barriers, and mask decode
// over 2x the work; b64 P-stores halve the P-write op count. Phase-split
// (all QK+softmax, then all PV) with per-wave per-group P buffers (4 KB/wave)
// keeps groups decoupled without barriers. LDS = 16+16+32 = 64 KB.
// ---------------------------------------------------------------------------
__global__ __launch_bounds__(256) void attn_mfma(
    const unsigned short* __restrict__ q,
    const unsigned short* __restrict__ k,
    const unsigned short* __restrict__ vt,
    const float* __restrict__ maddf,
    const unsigned int* __restrict__ flags,
    unsigned short* __restrict__ out)
{
    __shared__ unsigned short Ks[2][64 * 64];    // 16 KB
    __shared__ unsigned short Vs[2][64 * 64];    // 16 KB [dv][key]
    __shared__ unsigned short Ps[4][4][16 * 64]; // 32 KB, per wave per q-group
    const int t = threadIdx.x;
    const int w = t >> 6, l = t & 63;
    const int quad = l >> 4, l16 = l & 15;

    const int bid = blockIdx.x;                  // 512 blocks = 8 * 64
    const int swz = (bid & 7) * 64 + (bid >> 3); // bijective XCD swizzle
    const int qb = swz & 7, h = (swz >> 3) & 15, b = swz >> 7;
    const int q0 = qb * 256;
    const size_t hb = ((size_t)b * H_ + h) * S_;

    const int srow8 = l >> 3;
    const int sch   = (l & 7) ^ srow8;
    const int rsw   = l16 & 7;

    // Q fragments direct from global (pre-scaled by 0.125*log2e in projection)
    const unsigned short* qg = q + (hb + q0) * HD_;
    bf16x8 qf[4][2];   // [q-group][d-half], B-operand frags (row-major [q][d])
    #pragma unroll
    for (int g = 0; g < 4; ++g)
        #pragma unroll
        for (int c = 0; c < 2; ++c)
            qf[g][c] = *(const bf16x8*)(qg +
                (size_t)(w * 64 + g * 16 + l16) * HD_ + (c * 4 + quad) * 8);

    const bf16x8 onesf = {(short)0x3F80, (short)0x3F80, (short)0x3F80, (short)0x3F80,
                          (short)0x3F80, (short)0x3F80, (short)0x3F80, (short)0x3F80};

    const f32x4 fz = {0.f, 0.f, 0.f, 0.f};
    f32x4 o[4][4];
    f32x4 ol[4] = {fz, fz, fz, fz};              // ones-MFMA row-sum accumulator
    #pragma unroll
    for (int g = 0; g < 4; ++g)
        #pragma unroll
        for (int jv = 0; jv < 4; ++jv) o[g][jv] = fz;

    const unsigned short* kg0 = k + hb * HD_;
    const unsigned short* vg0 = vt + ((size_t)b * H_ + h) * HD_ * S_;

    // stage K/V tile kt into buffer d (swizzled 16B chunks, 2 async16 each)
    auto stage = [&](int d, int kt) {
        #pragma unroll
        for (int s = 0; s < 2; ++s) {
            int r0 = w * 16 + s * 8;
            int rr = r0 + srow8;
            async16(kg0 + (size_t)(kt * 64 + rr) * HD_ + sch * 8, &Ks[d][r0 * 64]);
            async16(vg0 + (size_t)rr * S_ + kt * 64 + sch * 8, &Vs[d][r0 * 64]);
        }
    };

    stage(0, 0);
    int cur = 0;
    for (int kt = 0; kt < S_ / 64; ++kt) {
        // drains the in-flight global_load_lds for buf[cur] (compiler emits
        // vmcnt(0) before s_barrier) and joins all waves past last tile's use
        // of buf[cur^1].
        __syncthreads();
        if (kt + 1 < S_ / 64) stage(cur ^ 1, kt + 1);

        const int allv = flags[b * (S_ / 64) + kt];   // uniform -> scalar load
        float madd[4][4];
        if (!allv) {
            #pragma unroll
            for (int kk = 0; kk < 4; ++kk) {
                float4 mv = *(const float4*)&maddf[(size_t)b * S_ + kt * 64 + kk * 16 + quad * 4];
                madd[kk][0] = mv.x; madd[kk][1] = mv.y;
                madd[kk][2] = mv.z; madd[kk][3] = mv.w;
            }
        }

        // ---- phase 1: K frags, QK^T + softmax for all 4 groups ----
        const unsigned short* Kc = &Ks[cur][0];
        bf16x8 kf[4][2];
        #pragma unroll
        for (int kk = 0; kk < 4; ++kk) {
            int row = kk * 16 + l16;
            #pragma unroll
            for (int c = 0; c < 2; ++c)
                kf[kk][c] = *(const bf16x8*)&Kc[row * 64 + (((c * 4 + quad) ^ rsw) * 8)];
        }
        #pragma unroll
        for (int g = 0; g < 4; ++g) {
            // scores: D[key = kk*16 + quad*4 + r][q = g*16 + l16]
            f32x4 sc[4];
            #pragma unroll
            for (int kk = 0; kk < 4; ++kk) sc[kk] = fz;
            __builtin_amdgcn_s_setprio(1);
            #pragma unroll
            for (int kk = 0; kk < 4; ++kk) {
                sc[kk] = MFMA16(kf[kk][0], qf[g][0], sc[kk]);
                sc[kk] = MFMA16(kf[kk][1], qf[g][1], sc[kk]);
            }
            __builtin_amdgcn_s_setprio(0);
            if (allv) softmax_store<false>(sc, madd, &Ps[w][g][0], l16, quad, rsw);
            else      softmax_store<true >(sc, madd, &Ps[w][g][0], l16, quad, rsw);
        }

        // ---- phase 2: V frags, PV (+ ones row-sum) for all 4 groups ----
        const unsigned short* Vc = &Vs[cur][0];
        bf16x8 vfr[4][2];
        #pragma unroll
        for (int jv = 0; jv < 4; ++jv) {
            int row = jv * 16 + l16;
            #pragma unroll
            for (int c = 0; c < 2; ++c)
                vfr[jv][c] = *(const bf16x8*)&Vc[row * 64 + (((c * 4 + quad) ^ rsw) * 8)];
        }
        #pragma unroll
        for (int g = 0; g < 4; ++g) {
            // PV: A = P^[q=l16][key], B = V rows [dv][key]; O D[q=quad*4+r][dv=l16]
            bf16x8 pa0 = *(const bf16x8*)&Ps[w][g][l16 * 64 + ((quad ^ rsw) * 8)];
            bf16x8 pa1 = *(const bf16x8*)&Ps[w][g][l16 * 64 + (((4 + quad) ^ rsw) * 8)];
            __builtin_amdgcn_s_setprio(1);
            #pragma unroll
            for (int jv = 0; jv < 4; ++jv) {
                o[g][jv] = MFMA16(pa0, vfr[jv][0], o[g][jv]);
                o[g][jv] = MFMA16(pa1, vfr[jv][1], o[g][jv]);
            }
            ol[g] = MFMA16(pa0, onesf, ol[g]);
            ol[g] = MFMA16(pa1, onesf, ol[g]);
            __builtin_amdgcn_s_setprio(0);
        }
        cur ^= 1;
    }

    // epilogue: ol[g][r] = full row sum for q-row (g, quad*4+r); no shuffles.
    #pragma unroll
    for (int g = 0; g < 4; ++g) {
        float inv[4];
        #pragma unroll
        for (int r = 0; r < 4; ++r) inv[r] = 1.0f / ol[g][r];
        #pragma unroll
        for (int jv = 0; jv < 4; ++jv) {
            int col = h * HD_ + jv * 16 + l16;
            #pragma unroll
            for (int r = 0; r < 4; ++r) {
                int row = q0 + w * 64 + g * 16 + quad * 4 + r;
                out[((size_t)b * S_ + row) * DM_ + col] = f2bf(o[g][jv][r] * inv[r]);
            }
        }
    }
}

extern "C" void kernel_launch(void* const* d_in, const int* in_sizes, int n_in,
                              void* d_out, int out_size, void* d_ws, size_t ws_size,
                              hipStream_t stream) {
    const float* Q    = (const float*)d_in[0];
    const float* K    = (const float*)d_in[1];
    const float* V    = (const float*)d_in[2];
    const int*   mask = (const int*)d_in[3];
    const float* Wq   = (const float*)d_in[4];
    const float* bq   = (const float*)d_in[5];
    const float* Wk   = (const float*)d_in[6];
    const float* bk   = (const float*)d_in[7];
    const float* Wv   = (const float*)d_in[8];
    const float* bv   = (const float*)d_in[9];
    const float* Wo   = (const float*)d_in[10];
    const float* bo   = (const float*)d_in[11];

    char* ws = (char*)d_ws;
    const size_t MB = 1024 * 1024;
    unsigned short* Qc  = (unsigned short*)(ws);            // 16 MB each
    unsigned short* Kc  = (unsigned short*)(ws + 16 * MB);
    unsigned short* Vc  = (unsigned short*)(ws + 32 * MB);
    unsigned short* Wqt = (unsigned short*)(ws + 48 * MB);  // 2 MB each
    unsigned short* Wkt = (unsigned short*)(ws + 50 * MB);
    unsigned short* Wvt = (unsigned short*)(ws + 52 * MB);
    unsigned short* Wot = (unsigned short*)(ws + 54 * MB);
    unsigned short* qh  = (unsigned short*)(ws + 56 * MB);  // [B,H,S,64]
    unsigned short* kh  = (unsigned short*)(ws + 72 * MB);
    unsigned short* vth = (unsigned short*)(ws + 88 * MB);  // [B,H,64,S]
    unsigned short* ao  = (unsigned short*)(ws + 104 * MB); // [B,S,DM]
    float*          maddf = (float*)(ws + 120 * MB);        // 32 KB
    unsigned int*   flagsb = (unsigned int*)(ws + 120 * MB + 64 * 1024); // 512 B

    prep_all<<<dim3(13344), 256, 0, stream>>>(
        Q, K, V, mask, Wq, Wk, Wv, Wo,
        Qc, Kc, Vc, Wqt, Wkt, Wvt, Wot, maddf, flagsb);
    gemm_qkv3<<<dim3(1536), 512, 0, stream>>>(
        Qc, Kc, Vc, Wqt, Wkt, Wvt, bq, bk, bv, qh, kh, vth);
    attn_mfma<<<dim3(512), 256, 0, stream>>>(
        qh, kh, vth, maddf, flagsb, ao);
    gemm_omfma<<<dim3(512), 512, 0, stream>>>(ao, Wot, bo, (float*)d_out);
}